// Round 9
// baseline (250.880 us; speedup 1.0000x reference)
//
#include <hip/hip_runtime.h>

// Problem constants
#define BB   4
#define CC   128
#define DHW  32768           // 32*32*32
#define NN   131072          // BB*DHW
#define KK   1024

// Output layout (floats, concatenated in reference return order)
#define OUT_Q    0
#define OUT_LOSS 16777216
#define OUT_IDX  16777217
#define OUT_ESUM 16908289
#define OUT_EMB  16908545

// Workspace layout (float offsets).
#define WS_ENH   131072      // 1024 floats: 0.5*||e_k||^2
#define WS_CNT   132096      // 1 int rescue counter
#define WS_LPART 132112      // 128 floats: spread loss partials
#define WS_LIST  263172      // 131072 ints rescue list
#define WS_EMBH  394244      // 65536 floats: fp16 codebook fragments (256 KB)

// fp16 single-product key error: sigma ~0.006-0.007. EPS = 0.0625 ~ 9-10
// sigma: flagged set is a superset of ambiguous vectors (indices must be
// EXACT -- one mis-tie can exceed the absmax threshold).
#define EPS_GAP  0.0625f

typedef __attribute__((ext_vector_type(8))) _Float16  half8;   // 8 x fp16
typedef __attribute__((ext_vector_type(4))) float     f32x4;

// ---------------------------------------------------------------------------
// prep: one sweep over emb builds everything emb-derived:
//  - fp16 A-operand fragments (A[m=code-in-group][k=channel]; per-lane
//    m=lane&15, k=(lane>>4)*8+j; layout embH[cc*256 + kc*64 + lane])
//  - enh[k] = 0.5*||e_k||^2
//  - OUT_EMB copy, OUT_ESUM zeros, loss partials + cnt zero (block 0)
// ---------------------------------------------------------------------------
__global__ __launch_bounds__(256) void prep_kernel(const float* __restrict__ emb,
                                                   half8* __restrict__ embH,
                                                   float* __restrict__ enh,
                                                   float* __restrict__ lpart,
                                                   int* __restrict__ cnt,
                                                   float* __restrict__ out) {
    const int cc   = blockIdx.x;        // 0..63 (16 codes each)
    const int t    = threadIdx.x;
    const int kc   = t >> 6;            // 0..3
    const int lane = t & 63;
    const int l15  = lane & 15;
    const int code = cc * 16 + l15;
    const int cb   = kc * 32 + (lane >> 4) * 8;
    const float* src = emb + code * CC + cb;

    half8 h;
    float s = 0.f;
    #pragma unroll
    for (int j = 0; j < 8; ++j) {
        float v = src[j];
        s = fmaf(v, v, s);
        h[j] = (_Float16)v;
    }
    embH[cc * 256 + kc * 64 + lane] = h;

    // reduce ||e||^2 per code: within wave over the 4 quads, then across waves
    s += __shfl_xor(s, 16, 64);
    s += __shfl_xor(s, 32, 64);
    __shared__ float part[4][16];
    if (lane < 16) part[kc][l15] = s;
    __syncthreads();
    if (t < 16)
        enh[cc * 16 + t] = 0.5f * (part[0][t] + part[1][t] + part[2][t] + part[3][t]);

    // OUT_EMB copy: this block's 2048-float slice (2 float4 per thread)
    {
        const float4* es = (const float4*)(emb + cc * 2048) + t;
        float4*       eo = (float4*)(out + OUT_EMB + cc * 2048) + t;
        eo[0]   = es[0];
        eo[256] = es[256];
    }
    if (cc == 0) {
        if (t == 0) *cnt = 0;
        if (t < 128) lpart[t] = 0.0f;
        out[OUT_ESUM + t] = 0.0f;      // 256 zeros
    }
}

// ---------------------------------------------------------------------------
// argmin v12: fp16 MFMA, 1-wave blocks (4096), ZERO LDS / ZERO barriers,
// depth-2 REGISTER pipeline on the codebook fragments: while the MFMAs of
// group cc / cc+1 execute, the loads for cc+2 / cc+3 are in flight (hides
// ~200-cyc L2 latency; VGPR 56->~120 is free at the 16-waves/CU grid cap).
// enh read direct from L1/L2 (4 KB, hot). Fused epilogue: float idx write,
// loss ||x||^2 - 2*best_key into spread partials, transpose-store Q.
// ---------------------------------------------------------------------------
__global__ __launch_bounds__(64) __attribute__((amdgpu_waves_per_eu(4, 8)))
void argmin_kernel(const float* __restrict__ x,
                   const half8* __restrict__ embH,
                   const float* __restrict__ enh,
                   const float* __restrict__ emb,
                   int* __restrict__ cnt,
                   int* __restrict__ list,
                   float* __restrict__ out,
                   float* __restrict__ lpart) {
    const int lane = threadIdx.x;       // 0..63 (one wave per block)
    const int quad = lane >> 4;
    const int l15  = lane & 15;

    const int n_wave = blockIdx.x * 32;
    const int b      = n_wave >> 15;
    const int dhw0   = n_wave & (DHW - 1);
    const float* __restrict__ xb = x + (size_t)b * CC * DHW + dhw0;

    // Build x fragments (B operand, fp16): B[k=quad*8+j][n=vec=l15] per tile.
    half8 x_h[2][4];
    float xsq[2] = {0.f, 0.f};
    #pragma unroll
    for (int tile = 0; tile < 2; ++tile) {
        const int voff = tile * 16 + l15;
        #pragma unroll
        for (int kc = 0; kc < 4; ++kc) {
            const int c0 = kc * 32 + quad * 8;
            #pragma unroll
            for (int j = 0; j < 8; ++j) {
                float v = xb[(size_t)(c0 + j) * DHW + voff];
                xsq[tile] = fmaf(v, v, xsq[tile]);
                x_h[tile][kc][j] = (_Float16)v;
            }
        }
    }

    // best-2 per lane, one vector per tile (v = tile*16 + l15), max-key form.
    float bv1[2] = {-1e30f, -1e30f};
    float bv2[2] = {-1e30f, -1e30f};
    int   bi1[2] = {0, 0};

    #define TRACK(A0, A1, CBASE)                                   \
        _Pragma("unroll")                                          \
        for (int r = 0; r < 4; ++r) {                              \
            const int code = (CBASE) + r;                          \
            const float k0 = (A0)[r];                              \
            bv2[0] = fminf(fmaxf(k0, bv2[0]), bv1[0]);             \
            if (k0 > bv1[0]) { bv1[0] = k0; bi1[0] = code; }       \
            const float k1 = (A1)[r];                              \
            bv2[1] = fminf(fmaxf(k1, bv2[1]), bv1[1]);             \
            if (k1 > bv1[1]) { bv1[1] = k1; bi1[1] = code; }       \
        }

    const half8* fb = embH + lane;
    const float* ep = enh + quad * 4;

    // prime the depth-2 pipeline: groups 0 (A) and 1 (B)
    half8 fA0 = fb[0],   fA1 = fb[64],  fA2 = fb[128], fA3 = fb[192];
    half8 fB0 = fb[256], fB1 = fb[320], fB2 = fb[384], fB3 = fb[448];
    f32x4 ehA = *(const f32x4*)(ep);
    f32x4 ehB = *(const f32x4*)(ep + 16);

    for (int cc = 0; cc < 64; cc += 2) {
        // ---- even slot (group cc, fragments fA) ----
        f32x4 acc0 = -ehA, acc1 = -ehA;
        acc0 = __builtin_amdgcn_mfma_f32_16x16x32_f16(fA0, x_h[0][0], acc0, 0, 0, 0);
        acc1 = __builtin_amdgcn_mfma_f32_16x16x32_f16(fA0, x_h[1][0], acc1, 0, 0, 0);
        acc0 = __builtin_amdgcn_mfma_f32_16x16x32_f16(fA1, x_h[0][1], acc0, 0, 0, 0);
        acc1 = __builtin_amdgcn_mfma_f32_16x16x32_f16(fA1, x_h[1][1], acc1, 0, 0, 0);
        acc0 = __builtin_amdgcn_mfma_f32_16x16x32_f16(fA2, x_h[0][2], acc0, 0, 0, 0);
        acc1 = __builtin_amdgcn_mfma_f32_16x16x32_f16(fA2, x_h[1][2], acc1, 0, 0, 0);
        acc0 = __builtin_amdgcn_mfma_f32_16x16x32_f16(fA3, x_h[0][3], acc0, 0, 0, 0);
        acc1 = __builtin_amdgcn_mfma_f32_16x16x32_f16(fA3, x_h[1][3], acc1, 0, 0, 0);
        if (cc + 2 < 64) {   // prefetch group cc+2 into fA (overlaps tracking+B-slot)
            const half8* nf = fb + (cc + 2) * 256;
            fA0 = nf[0]; fA1 = nf[64]; fA2 = nf[128]; fA3 = nf[192];
            ehA = *(const f32x4*)(ep + (cc + 2) * 16);
        }
        TRACK(acc0, acc1, cc * 16 + quad * 4)

        // ---- odd slot (group cc+1, fragments fB) ----
        f32x4 acc2 = -ehB, acc3 = -ehB;
        acc2 = __builtin_amdgcn_mfma_f32_16x16x32_f16(fB0, x_h[0][0], acc2, 0, 0, 0);
        acc3 = __builtin_amdgcn_mfma_f32_16x16x32_f16(fB0, x_h[1][0], acc3, 0, 0, 0);
        acc2 = __builtin_amdgcn_mfma_f32_16x16x32_f16(fB1, x_h[0][1], acc2, 0, 0, 0);
        acc3 = __builtin_amdgcn_mfma_f32_16x16x32_f16(fB1, x_h[1][1], acc3, 0, 0, 0);
        acc2 = __builtin_amdgcn_mfma_f32_16x16x32_f16(fB2, x_h[0][2], acc2, 0, 0, 0);
        acc3 = __builtin_amdgcn_mfma_f32_16x16x32_f16(fB2, x_h[1][2], acc3, 0, 0, 0);
        acc2 = __builtin_amdgcn_mfma_f32_16x16x32_f16(fB3, x_h[0][3], acc2, 0, 0, 0);
        acc3 = __builtin_amdgcn_mfma_f32_16x16x32_f16(fB3, x_h[1][3], acc3, 0, 0, 0);
        if (cc + 3 < 64) {   // prefetch group cc+3 into fB
            const half8* nf = fb + (cc + 3) * 256;
            fB0 = nf[0]; fB1 = nf[64]; fB2 = nf[128]; fB3 = nf[192];
            ehB = *(const f32x4*)(ep + (cc + 3) * 16);
        }
        TRACK(acc2, acc3, (cc + 1) * 16 + quad * 4)
    }
    #undef TRACK

    // Merge the 4 quads holding the same vector; butterfly leaves all lanes
    // with the merged result. Sum ||x||^2 along the way.
    float lsum = 0.f;
    int mIdx[2];
    #pragma unroll
    for (int tile = 0; tile < 2; ++tile) {
        float v1 = bv1[tile], v2 = bv2[tile], xq = xsq[tile];
        int   i1 = bi1[tile];
        #pragma unroll
        for (int off = 16; off < 64; off <<= 1) {
            float ov1 = __shfl_xor(v1, off, 64);
            int   oi1 = __shfl_xor(i1, off, 64);
            float ov2 = __shfl_xor(v2, off, 64);
            xq += __shfl_xor(xq, off, 64);
            bool take = (ov1 > v1) || (ov1 == v1 && oi1 < i1);
            float loser = take ? v1 : ov1;
            if (take) { v1 = ov1; i1 = oi1; }
            v2 = fmaxf(fmaxf(v2, ov2), loser);
        }
        mIdx[tile] = i1;
        if (lane < 16) {   // quad 0 owns the vector
            const int n = n_wave + tile * 16 + l15;
            out[OUT_IDX + n] = (float)i1;
            lsum += xq - 2.0f * v1;            // Sum_c (q_c - x_c)^2
            if (v1 - v2 < EPS_GAP) {           // near-tie -> exact rescore
                int pos = atomicAdd(cnt, 1);
                list[pos] = n;
            }
        }
    }

    // wave loss partial -> one of 128 spread slots (contention /128)
    #pragma unroll
    for (int o = 32; o > 0; o >>= 1) lsum += __shfl_down(lsum, o);
    if (lane == 0) atomicAdd(&lpart[blockIdx.x & 127], lsum);

    // Fused quantize write, 4x4 transpose form. Lane owns 4 consecutive
    // vectors (vq = lane&7) x 16 channels (cb = lane>>3); per c-quad: 4 emb
    // float4 loads (L2-hot) -> transpose -> 4 float4 stores along dhw.
    {
        const int vq = lane & 7;
        const int cb = lane >> 3;
        int code[4];
        #pragma unroll
        for (int j = 0; j < 4; ++j) {
            const int w  = (4 * vq + j) & 15;
            const int cA = __shfl(mIdx[0], w, 64);
            const int cB = __shfl(mIdx[1], w, 64);
            code[j] = (vq < 4) ? cA : cB;
        }
        const float* e0 = emb + code[0] * CC + cb * 16;
        const float* e1 = emb + code[1] * CC + cb * 16;
        const float* e2 = emb + code[2] * CC + cb * 16;
        const float* e3 = emb + code[3] * CC + cb * 16;
        float* op = out + OUT_Q + (size_t)b * CC * DHW + (size_t)(cb * 16) * DHW
                    + dhw0 + 4 * vq;
        #pragma unroll
        for (int cq = 0; cq < 4; ++cq) {
            const float4 r0 = *(const float4*)(e0 + cq * 4);
            const float4 r1 = *(const float4*)(e1 + cq * 4);
            const float4 r2 = *(const float4*)(e2 + cq * 4);
            const float4 r3 = *(const float4*)(e3 + cq * 4);
            *(float4*)(op + (size_t)(cq * 4 + 0) * DHW) = make_float4(r0.x, r1.x, r2.x, r3.x);
            *(float4*)(op + (size_t)(cq * 4 + 1) * DHW) = make_float4(r0.y, r1.y, r2.y, r3.y);
            *(float4*)(op + (size_t)(cq * 4 + 2) * DHW) = make_float4(r0.z, r1.z, r2.z, r3.z);
            *(float4*)(op + (size_t)(cq * 4 + 3) * DHW) = make_float4(r0.w, r1.w, r2.w, r3.w);
        }
    }
}

// ---------------------------------------------------------------------------
// rescue: exact fp32 argmin for flagged near-tie vectors, batched 4/block.
// xs packed [c][4] so the inner loop per c-quad is 4 ds_read_b128 broadcasts
// + 1 global float4 + 16 FMA (was 16 scalar LDS reads). Rewrites the float
// index and the quantized-output row. Block 0 folds the 128 loss partials.
// ---------------------------------------------------------------------------
#define RENT 4
__global__ __launch_bounds__(256) void rescue_kernel(const float* __restrict__ x,
                                                     const float* __restrict__ emb,
                                                     const float* __restrict__ enh,
                                                     const int* __restrict__ cnt,
                                                     const int* __restrict__ list,
                                                     const float* __restrict__ lpart,
                                                     float* __restrict__ out) {
    __shared__ float xs4[CC][RENT];   // [channel][entry]
    __shared__ int   ns[RENT];
    __shared__ float rv[256];
    __shared__ int   ri[256];
    const int m = *cnt;
    const int t = threadIdx.x;

    if (blockIdx.x == 0 && t < 64) {
        float s = lpart[t] + lpart[t + 64];
        #pragma unroll
        for (int o = 32; o > 0; o >>= 1) s += __shfl_down(s, o);
        if (t == 0) out[OUT_LOSS] = 2.5f * s / 16777216.0f;
    }

    for (int base = blockIdx.x * RENT; base < m; base += gridDim.x * RENT) {
        const int nb = min(RENT, m - base);

        {
            const int c  = t & 127;
            const int e0 = t >> 7;
            for (int e = e0; e < nb; e += 2) {
                const int n   = list[base + e];
                const int bb  = n >> 15;
                const int dhw = n & (DHW - 1);
                xs4[c][e] = x[(size_t)bb * CC * DHW + (size_t)c * DHW + dhw];
                if (c == 0) ns[e] = n;
            }
        }
        __syncthreads();

        float bv[RENT] = {1e30f, 1e30f, 1e30f, 1e30f};
        int   bi[RENT] = {0, 0, 0, 0};
        for (int k0 = 0; k0 < 4; ++k0) {
            const int k = k0 * 256 + t;
            const float4* ekv = (const float4*)(emb + k * CC);
            float s0 = 0.f, s1 = 0.f, s2 = 0.f, s3 = 0.f;
            #pragma unroll 8
            for (int c4 = 0; c4 < 32; ++c4) {
                const float4 e4 = ekv[c4];
                const float4 xa = *(const float4*)xs4[c4 * 4 + 0];
                const float4 xb2 = *(const float4*)xs4[c4 * 4 + 1];
                const float4 xc = *(const float4*)xs4[c4 * 4 + 2];
                const float4 xd = *(const float4*)xs4[c4 * 4 + 3];
                s0 = fmaf(e4.x, xa.x, s0); s0 = fmaf(e4.y, xb2.x, s0);
                s0 = fmaf(e4.z, xc.x, s0); s0 = fmaf(e4.w, xd.x, s0);
                s1 = fmaf(e4.x, xa.y, s1); s1 = fmaf(e4.y, xb2.y, s1);
                s1 = fmaf(e4.z, xc.y, s1); s1 = fmaf(e4.w, xd.y, s1);
                s2 = fmaf(e4.x, xa.z, s2); s2 = fmaf(e4.y, xb2.z, s2);
                s2 = fmaf(e4.z, xc.z, s2); s2 = fmaf(e4.w, xd.z, s2);
                s3 = fmaf(e4.x, xa.w, s3); s3 = fmaf(e4.y, xb2.w, s3);
                s3 = fmaf(e4.z, xc.w, s3); s3 = fmaf(e4.w, xd.w, s3);
            }
            const float eh = enh[k];
            const float key0 = eh - s0;
            if (key0 < bv[0] || (key0 == bv[0] && k < bi[0])) { bv[0] = key0; bi[0] = k; }
            const float key1 = eh - s1;
            if (key1 < bv[1] || (key1 == bv[1] && k < bi[1])) { bv[1] = key1; bi[1] = k; }
            const float key2 = eh - s2;
            if (key2 < bv[2] || (key2 == bv[2] && k < bi[2])) { bv[2] = key2; bi[2] = k; }
            const float key3 = eh - s3;
            if (key3 < bv[3] || (key3 == bv[3] && k < bi[3])) { bv[3] = key3; bi[3] = k; }
        }

        #pragma unroll
        for (int e = 0; e < RENT; ++e) {
            if (e >= nb) break;
            __syncthreads();
            rv[t] = bv[e]; ri[t] = bi[e];
            __syncthreads();
            for (int s = 128; s > 0; s >>= 1) {
                if (t < s) {
                    float ov = rv[t + s]; int oi = ri[t + s];
                    if (ov < rv[t] || (ov == rv[t] && oi < ri[t])) {
                        rv[t] = ov; ri[t] = oi;
                    }
                }
                __syncthreads();
            }
            const int code = ri[0];
            const int n    = ns[e];
            const int bb   = n >> 15;
            const int dhw  = n & (DHW - 1);
            if (t == 0) out[OUT_IDX + n] = (float)code;
            if (t < CC)
                out[OUT_Q + (size_t)bb * CC * DHW + (size_t)t * DHW + dhw] =
                    emb[code * CC + t];
        }
        __syncthreads();
    }
}

extern "C" void kernel_launch(void* const* d_in, const int* in_sizes, int n_in,
                              void* d_out, int out_size, void* d_ws, size_t ws_size,
                              hipStream_t stream) {
    const float* x   = (const float*)d_in[0];   // [4,128,32,32,32] fp32
    const float* emb = (const float*)d_in[1];   // [1024,128] fp32
    float* out = (float*)d_out;
    float* ws  = (float*)d_ws;

    float*  enh   = ws + WS_ENH;
    int*    cnt   = (int*)(ws + WS_CNT);
    float*  lpart = ws + WS_LPART;
    int*    list  = (int*)(ws + WS_LIST);
    half8*  embH  = (half8*)(ws + WS_EMBH);

    prep_kernel<<<64, 256, 0, stream>>>(emb, embH, enh, lpart, cnt, out);
    argmin_kernel<<<NN / 32, 64, 0, stream>>>(x, embH, enh, emb, cnt, list, out, lpart);
    rescue_kernel<<<1024, 256, 0, stream>>>(x, emb, enh, cnt, list, lpart, out);
}

// Round 10
// 194.496 us; speedup vs baseline: 1.2899x; 1.2899x over previous
//
#include <hip/hip_runtime.h>

// Problem constants
#define BB   4
#define CC   128
#define DHW  32768           // 32*32*32
#define NN   131072          // BB*DHW
#define KK   1024

// Output layout (floats, concatenated in reference return order)
#define OUT_Q    0
#define OUT_LOSS 16777216
#define OUT_IDX  16777217
#define OUT_ESUM 16908289
#define OUT_EMB  16908545

// Workspace layout (float offsets).
#define WS_EMBT  0           // 131072 floats: embT[c][k] fp32 (rescue, coalesced)
#define WS_ENH   131072      // 1024 floats: 0.5*||e_k||^2
#define WS_CNT   132096      // 1 int rescue counter
#define WS_LPART 132112      // 128 floats: spread loss partials
#define WS_LIST  263172      // 131072 ints rescue list
#define WS_EMBH  394244      // 65536 floats: fp16 codebook fragments (256 KB)

// fp16 single-product key error: sigma ~0.006-0.008. EPS = 0.0625 ~ 8-10
// sigma: flagged set is a superset of ambiguous vectors (indices must be
// EXACT -- one mis-tie can exceed the absmax threshold).
#define EPS_GAP  0.0625f

typedef __attribute__((ext_vector_type(8))) _Float16  half8;   // 8 x fp16
typedef __attribute__((ext_vector_type(4))) float     f32x4;

// ---------------------------------------------------------------------------
// prep: one sweep over emb builds everything emb-derived:
//  - fp16 A-operand fragments (A[m=code-in-group][k=channel]; per-lane
//    m=lane&15, k=(lane>>4)*8+j; layout embH[cc*256 + kc*64 + lane])
//  - embT[c][k] fp32 transpose (rescue's coalesced read path)
//  - enh[k] = 0.5*||e_k||^2
//  - OUT_EMB copy, OUT_ESUM zeros, loss partials + cnt zero (block 0)
// ---------------------------------------------------------------------------
__global__ __launch_bounds__(256) void prep_kernel(const float* __restrict__ emb,
                                                   half8* __restrict__ embH,
                                                   float* __restrict__ embT,
                                                   float* __restrict__ enh,
                                                   float* __restrict__ lpart,
                                                   int* __restrict__ cnt,
                                                   float* __restrict__ out) {
    const int cc   = blockIdx.x;        // 0..63 (16 codes each)
    const int t    = threadIdx.x;
    const int kc   = t >> 6;            // 0..3
    const int lane = t & 63;
    const int l15  = lane & 15;
    const int code = cc * 16 + l15;
    const int cb   = kc * 32 + (lane >> 4) * 8;
    const float* src = emb + code * CC + cb;

    half8 h;
    float s = 0.f;
    #pragma unroll
    for (int j = 0; j < 8; ++j) {
        float v = src[j];
        s = fmaf(v, v, s);
        h[j] = (_Float16)v;
        embT[(cb + j) * KK + code] = v;    // fp32 transpose (one-time scatter)
    }
    embH[cc * 256 + kc * 64 + lane] = h;

    // reduce ||e||^2 per code: within wave over the 4 quads, then across waves
    s += __shfl_xor(s, 16, 64);
    s += __shfl_xor(s, 32, 64);
    __shared__ float part[4][16];
    if (lane < 16) part[kc][l15] = s;
    __syncthreads();
    if (t < 16)
        enh[cc * 16 + t] = 0.5f * (part[0][t] + part[1][t] + part[2][t] + part[3][t]);

    // OUT_EMB copy: this block's 2048-float slice (2 float4 per thread)
    {
        const float4* es = (const float4*)(emb + cc * 2048) + t;
        float4*       eo = (float4*)(out + OUT_EMB + cc * 2048) + t;
        eo[0]   = es[0];
        eo[256] = es[256];
    }
    if (cc == 0) {
        if (t == 0) *cnt = 0;
        if (t < 128) lpart[t] = 0.0f;
        out[OUT_ESUM + t] = 0.0f;      // 256 zeros
    }
}

// ---------------------------------------------------------------------------
// argmin v13: round-8's proven 4-wave structure (256 thr, LDS ehs, VGPR-lean)
// + depth-2 REGISTER prefetch on codebook fragments, with waves_per_eu(4,4)
// pinning the register budget at 128 (grid already caps residency at 16
// waves/CU, so VGPR 56->~100 is free). Round-9's spill (VGPR forced to the
// 64-bucket by waves_per_eu(4,8) -> 39 MB scratch) is thereby excluded.
// While group cc's 8 MFMAs execute, group cc+2's 4 loads are in flight.
// Fused epilogue: float idx write, loss ||x||^2 - 2*best_key into spread
// partials, transpose-store Q.
// ---------------------------------------------------------------------------
__global__ __launch_bounds__(256) __attribute__((amdgpu_waves_per_eu(4, 4)))
void argmin_kernel(const float* __restrict__ x,
                   const half8* __restrict__ embH,
                   const float* __restrict__ enh,
                   const float* __restrict__ emb,
                   int* __restrict__ cnt,
                   int* __restrict__ list,
                   float* __restrict__ out,
                   float* __restrict__ lpart) {
    __shared__ float ehs[KK];         // 4 KB: 0.5*||e||^2 staged once

    const int t    = threadIdx.x;
    const int wave = t >> 6;
    const int lane = t & 63;
    const int quad = lane >> 4;
    const int l15  = lane & 15;

    const int n_wave = blockIdx.x * 128 + wave * 32;
    const int b      = n_wave >> 15;
    const int dhw0   = n_wave & (DHW - 1);
    const float* __restrict__ xb = x + (size_t)b * CC * DHW + dhw0;

    #pragma unroll
    for (int j = 0; j < 4; ++j) ehs[j * 256 + t] = enh[j * 256 + t];

    // Build x fragments (B operand, fp16): B[k=quad*8+j][n=vec=l15] per tile.
    half8 x_h[2][4];
    float xsq[2] = {0.f, 0.f};
    #pragma unroll
    for (int tile = 0; tile < 2; ++tile) {
        const int voff = tile * 16 + l15;
        #pragma unroll
        for (int kc = 0; kc < 4; ++kc) {
            const int c0 = kc * 32 + quad * 8;
            #pragma unroll
            for (int j = 0; j < 8; ++j) {
                float v = xb[(size_t)(c0 + j) * DHW + voff];
                xsq[tile] = fmaf(v, v, xsq[tile]);
                x_h[tile][kc][j] = (_Float16)v;
            }
        }
    }

    // best-2 per lane, one vector per tile (v = tile*16 + l15), max-key form.
    float bv1[2] = {-1e30f, -1e30f};
    float bv2[2] = {-1e30f, -1e30f};
    int   bi1[2] = {0, 0};

    __syncthreads();  // ehs visible

    #define TRACK(A0, A1, CBASE)                                   \
        _Pragma("unroll")                                          \
        for (int r = 0; r < 4; ++r) {                              \
            const int code = (CBASE) + r;                          \
            const float k0 = (A0)[r];                              \
            bv2[0] = fminf(fmaxf(k0, bv2[0]), bv1[0]);             \
            if (k0 > bv1[0]) { bv1[0] = k0; bi1[0] = code; }       \
            const float k1 = (A1)[r];                              \
            bv2[1] = fminf(fmaxf(k1, bv2[1]), bv1[1]);             \
            if (k1 > bv1[1]) { bv1[1] = k1; bi1[1] = code; }       \
        }

    const half8* fb = embH + lane;

    // prime the depth-2 pipeline: groups 0 (A) and 1 (B)
    half8 fA0 = fb[0],   fA1 = fb[64],  fA2 = fb[128], fA3 = fb[192];
    half8 fB0 = fb[256], fB1 = fb[320], fB2 = fb[384], fB3 = fb[448];

    for (int cc = 0; cc < 64; cc += 2) {
        // ---- even slot (group cc, fragments fA) ----
        const f32x4 ehA = *(const f32x4*)&ehs[cc * 16 + quad * 4];
        f32x4 acc0 = -ehA, acc1 = -ehA;
        acc0 = __builtin_amdgcn_mfma_f32_16x16x32_f16(fA0, x_h[0][0], acc0, 0, 0, 0);
        acc1 = __builtin_amdgcn_mfma_f32_16x16x32_f16(fA0, x_h[1][0], acc1, 0, 0, 0);
        acc0 = __builtin_amdgcn_mfma_f32_16x16x32_f16(fA1, x_h[0][1], acc0, 0, 0, 0);
        acc1 = __builtin_amdgcn_mfma_f32_16x16x32_f16(fA1, x_h[1][1], acc1, 0, 0, 0);
        acc0 = __builtin_amdgcn_mfma_f32_16x16x32_f16(fA2, x_h[0][2], acc0, 0, 0, 0);
        acc1 = __builtin_amdgcn_mfma_f32_16x16x32_f16(fA2, x_h[1][2], acc1, 0, 0, 0);
        acc0 = __builtin_amdgcn_mfma_f32_16x16x32_f16(fA3, x_h[0][3], acc0, 0, 0, 0);
        acc1 = __builtin_amdgcn_mfma_f32_16x16x32_f16(fA3, x_h[1][3], acc1, 0, 0, 0);
        if (cc + 2 < 64) {   // prefetch group cc+2 (flies under tracking + B-slot)
            const half8* nf = fb + (cc + 2) * 256;
            fA0 = nf[0]; fA1 = nf[64]; fA2 = nf[128]; fA3 = nf[192];
        }
        TRACK(acc0, acc1, cc * 16 + quad * 4)

        // ---- odd slot (group cc+1, fragments fB) ----
        const f32x4 ehB = *(const f32x4*)&ehs[(cc + 1) * 16 + quad * 4];
        f32x4 acc2 = -ehB, acc3 = -ehB;
        acc2 = __builtin_amdgcn_mfma_f32_16x16x32_f16(fB0, x_h[0][0], acc2, 0, 0, 0);
        acc3 = __builtin_amdgcn_mfma_f32_16x16x32_f16(fB0, x_h[1][0], acc3, 0, 0, 0);
        acc2 = __builtin_amdgcn_mfma_f32_16x16x32_f16(fB1, x_h[0][1], acc2, 0, 0, 0);
        acc3 = __builtin_amdgcn_mfma_f32_16x16x32_f16(fB1, x_h[1][1], acc3, 0, 0, 0);
        acc2 = __builtin_amdgcn_mfma_f32_16x16x32_f16(fB2, x_h[0][2], acc2, 0, 0, 0);
        acc3 = __builtin_amdgcn_mfma_f32_16x16x32_f16(fB2, x_h[1][2], acc3, 0, 0, 0);
        acc2 = __builtin_amdgcn_mfma_f32_16x16x32_f16(fB3, x_h[0][3], acc2, 0, 0, 0);
        acc3 = __builtin_amdgcn_mfma_f32_16x16x32_f16(fB3, x_h[1][3], acc3, 0, 0, 0);
        if (cc + 3 < 64) {   // prefetch group cc+3
            const half8* nf = fb + (cc + 3) * 256;
            fB0 = nf[0]; fB1 = nf[64]; fB2 = nf[128]; fB3 = nf[192];
        }
        TRACK(acc2, acc3, (cc + 1) * 16 + quad * 4)
    }
    #undef TRACK

    // Merge the 4 quads holding the same vector; butterfly leaves all lanes
    // with the merged result. Sum ||x||^2 along the way.
    float lsum = 0.f;
    int mIdx[2];
    #pragma unroll
    for (int tile = 0; tile < 2; ++tile) {
        float v1 = bv1[tile], v2 = bv2[tile], xq = xsq[tile];
        int   i1 = bi1[tile];
        #pragma unroll
        for (int off = 16; off < 64; off <<= 1) {
            float ov1 = __shfl_xor(v1, off, 64);
            int   oi1 = __shfl_xor(i1, off, 64);
            float ov2 = __shfl_xor(v2, off, 64);
            xq += __shfl_xor(xq, off, 64);
            bool take = (ov1 > v1) || (ov1 == v1 && oi1 < i1);
            float loser = take ? v1 : ov1;
            if (take) { v1 = ov1; i1 = oi1; }
            v2 = fmaxf(fmaxf(v2, ov2), loser);
        }
        mIdx[tile] = i1;
        if (lane < 16) {   // quad 0 owns the vector
            const int n = n_wave + tile * 16 + l15;
            out[OUT_IDX + n] = (float)i1;
            lsum += xq - 2.0f * v1;            // Sum_c (q_c - x_c)^2
            if (v1 - v2 < EPS_GAP) {           // near-tie -> exact rescore
                int pos = atomicAdd(cnt, 1);
                list[pos] = n;
            }
        }
    }

    // wave loss partial -> one of 128 spread slots (contention /128)
    #pragma unroll
    for (int o = 32; o > 0; o >>= 1) lsum += __shfl_down(lsum, o);
    if (lane == 0) atomicAdd(&lpart[(blockIdx.x * 4 + wave) & 127], lsum);

    // Fused quantize write, 4x4 transpose form. Lane owns 4 consecutive
    // vectors (vq = lane&7) x 16 channels (cb = lane>>3); per c-quad: 4 emb
    // float4 loads (L2-hot) -> transpose -> 4 float4 stores along dhw.
    {
        const int vq = lane & 7;
        const int cb = lane >> 3;
        int code[4];
        #pragma unroll
        for (int j = 0; j < 4; ++j) {
            const int w  = (4 * vq + j) & 15;
            const int cA = __shfl(mIdx[0], w, 64);
            const int cB = __shfl(mIdx[1], w, 64);
            code[j] = (vq < 4) ? cA : cB;
        }
        const float* e0 = emb + code[0] * CC + cb * 16;
        const float* e1 = emb + code[1] * CC + cb * 16;
        const float* e2 = emb + code[2] * CC + cb * 16;
        const float* e3 = emb + code[3] * CC + cb * 16;
        float* op = out + OUT_Q + (size_t)b * CC * DHW + (size_t)(cb * 16) * DHW
                    + dhw0 + 4 * vq;
        #pragma unroll
        for (int cq = 0; cq < 4; ++cq) {
            const float4 r0 = *(const float4*)(e0 + cq * 4);
            const float4 r1 = *(const float4*)(e1 + cq * 4);
            const float4 r2 = *(const float4*)(e2 + cq * 4);
            const float4 r3 = *(const float4*)(e3 + cq * 4);
            *(float4*)(op + (size_t)(cq * 4 + 0) * DHW) = make_float4(r0.x, r1.x, r2.x, r3.x);
            *(float4*)(op + (size_t)(cq * 4 + 1) * DHW) = make_float4(r0.y, r1.y, r2.y, r3.y);
            *(float4*)(op + (size_t)(cq * 4 + 2) * DHW) = make_float4(r0.z, r1.z, r2.z, r3.z);
            *(float4*)(op + (size_t)(cq * 4 + 3) * DHW) = make_float4(r0.w, r1.w, r2.w, r3.w);
        }
    }
}

// ---------------------------------------------------------------------------
// rescue v3: exact fp32 argmin for flagged near-tie vectors, batched 4/block.
// Thread t owns codes 4t..4t+3; the codebook is read via embT[c][k] so each
// channel step is ONE coalesced float4 load (lane-consecutive k) + one LDS
// float4 broadcast + 16 FMA -- replaces round-9's lane-strided emb-row reads
// (64B line per 16B used, ~4x L2 over-traffic). Rewrites the float index and
// the quantized-output row. Block 0 folds the 128 loss partials.
// ---------------------------------------------------------------------------
#define RENT 4
__global__ __launch_bounds__(256) void rescue_kernel(const float* __restrict__ x,
                                                     const float* __restrict__ emb,
                                                     const float* __restrict__ embT,
                                                     const float* __restrict__ enh,
                                                     const int* __restrict__ cnt,
                                                     const int* __restrict__ list,
                                                     const float* __restrict__ lpart,
                                                     float* __restrict__ out) {
    __shared__ float xs4[CC][RENT];   // [channel][entry], float4-aligned rows
    __shared__ int   ns[RENT];
    __shared__ float rv[256];
    __shared__ int   ri[256];
    const int m = *cnt;
    const int t = threadIdx.x;

    if (blockIdx.x == 0 && t < 64) {
        float s = lpart[t] + lpart[t + 64];
        #pragma unroll
        for (int o = 32; o > 0; o >>= 1) s += __shfl_down(s, o);
        if (t == 0) out[OUT_LOSS] = 2.5f * s / 16777216.0f;
    }

    const float4* embT4 = (const float4*)embT;     // [c][k/4]
    const f32x4 enh4 = *(const f32x4*)&enh[4 * t]; // codes 4t..4t+3

    for (int base = blockIdx.x * RENT; base < m; base += gridDim.x * RENT) {
        const int nb = min(RENT, m - base);

        {
            const int c  = t & 127;
            const int e0 = t >> 7;
            for (int e = e0; e < nb; e += 2) {
                const int n   = list[base + e];
                const int bb  = n >> 15;
                const int dhw = n & (DHW - 1);
                xs4[c][e] = x[(size_t)bb * CC * DHW + (size_t)c * DHW + dhw];
                if (c == 0) ns[e] = n;
            }
        }
        __syncthreads();

        // s[e][j]: entry e dot codes 4t+j  (16 fp32 accumulators, static)
        f32x4 s0 = {0.f, 0.f, 0.f, 0.f};
        f32x4 s1 = {0.f, 0.f, 0.f, 0.f};
        f32x4 s2 = {0.f, 0.f, 0.f, 0.f};
        f32x4 s3 = {0.f, 0.f, 0.f, 0.f};
        #pragma unroll 8
        for (int c = 0; c < CC; ++c) {
            const float4 ev = embT4[c * 256 + t];         // embT[c][4t..4t+3]
            const float4 xv = *(const float4*)xs4[c];     // entries 0..3
            s0[0] = fmaf(ev.x, xv.x, s0[0]); s0[1] = fmaf(ev.y, xv.x, s0[1]);
            s0[2] = fmaf(ev.z, xv.x, s0[2]); s0[3] = fmaf(ev.w, xv.x, s0[3]);
            s1[0] = fmaf(ev.x, xv.y, s1[0]); s1[1] = fmaf(ev.y, xv.y, s1[1]);
            s1[2] = fmaf(ev.z, xv.y, s1[2]); s1[3] = fmaf(ev.w, xv.y, s1[3]);
            s2[0] = fmaf(ev.x, xv.z, s2[0]); s2[1] = fmaf(ev.y, xv.z, s2[1]);
            s2[2] = fmaf(ev.z, xv.z, s2[2]); s2[3] = fmaf(ev.w, xv.z, s2[3]);
            s3[0] = fmaf(ev.x, xv.w, s3[0]); s3[1] = fmaf(ev.y, xv.w, s3[1]);
            s3[2] = fmaf(ev.z, xv.w, s3[2]); s3[3] = fmaf(ev.w, xv.w, s3[3]);
        }

        // per-entry in-thread argmin over j (ascending -> lowest code on tie)
        float bv[RENT]; int bi[RENT];
        #define PICK(E, SE)                                        \
            {                                                      \
                float best = 1e30f; int bidx = 0;                  \
                _Pragma("unroll")                                  \
                for (int j = 0; j < 4; ++j) {                      \
                    const float key = enh4[j] - (SE)[j];           \
                    if (key < best) { best = key; bidx = 4 * t + j; } \
                }                                                  \
                bv[E] = best; bi[E] = bidx;                        \
            }
        PICK(0, s0) PICK(1, s1) PICK(2, s2) PICK(3, s3)
        #undef PICK

        #pragma unroll
        for (int e = 0; e < RENT; ++e) {
            if (e >= nb) break;
            __syncthreads();
            rv[t] = bv[e]; ri[t] = bi[e];
            __syncthreads();
            for (int s = 128; s > 0; s >>= 1) {
                if (t < s) {
                    float ov = rv[t + s]; int oi = ri[t + s];
                    if (ov < rv[t] || (ov == rv[t] && oi < ri[t])) {
                        rv[t] = ov; ri[t] = oi;
                    }
                }
                __syncthreads();
            }
            const int code = ri[0];
            const int n    = ns[e];
            const int bb   = n >> 15;
            const int dhw  = n & (DHW - 1);
            if (t == 0) out[OUT_IDX + n] = (float)code;
            if (t < CC)
                out[OUT_Q + (size_t)bb * CC * DHW + (size_t)t * DHW + dhw] =
                    emb[code * CC + t];
        }
        __syncthreads();
    }
}

extern "C" void kernel_launch(void* const* d_in, const int* in_sizes, int n_in,
                              void* d_out, int out_size, void* d_ws, size_t ws_size,
                              hipStream_t stream) {
    const float* x   = (const float*)d_in[0];   // [4,128,32,32,32] fp32
    const float* emb = (const float*)d_in[1];   // [1024,128] fp32
    float* out = (float*)d_out;
    float* ws  = (float*)d_ws;

    float*  embT  = ws + WS_EMBT;
    float*  enh   = ws + WS_ENH;
    int*    cnt   = (int*)(ws + WS_CNT);
    float*  lpart = ws + WS_LPART;
    int*    list  = (int*)(ws + WS_LIST);
    half8*  embH  = (half8*)(ws + WS_EMBH);

    prep_kernel<<<64, 256, 0, stream>>>(emb, embH, embT, enh, lpart, cnt, out);
    argmin_kernel<<<NN / 128, 256, 0, stream>>>(x, embH, enh, emb, cnt, list, out, lpart);
    rescue_kernel<<<1024, 256, 0, stream>>>(x, emb, embT, enh, cnt, list, lpart, out);
}